// Round 11
// baseline (125.124 us; speedup 1.0000x reference)
//
#include <hip/hip_runtime.h>
#include <math.h>

// RandomLowRes2D: per-image Gaussian blur (R=15, symmetric pad) + linear
// down/up resample along a per-image runtime axis.
//
// Fusion: low[j] = (1-fr)*s[la] + fr*s[la+1] collapses blur+downsample into a
// single fused filter on img: cw[k] = fmaf(fr, dwe[k], we[k+1]),
// with dwe[k] = we[k] - we[k+1] precomputed.
//
// Round 15 == Round 13 minus __builtin_nontemporal_load (two consecutive
// "container failed" rounds on the r13 binary; nt-LOAD is the only construct
// never exercised in a successful bench — replaced with plain vector loads.
// nt STORES stay: they ran fine in r12's measured 120.0us run).
//
// Round 13 structure (continue r12's winning direction: fewer, fatter
// blocks + hide fill latency; r12 showed consolidation pays, occupancy
// doesn't):
//  - grid (32, n_img): each block handles TWO tiles (16 rows).
//  - ax1 2-tile pipeline: fill A -> bar -> ISSUE B loads into registers
//    (T14 async split) -> low A -> bar -> {upsample A || write B->LDS,
//    disjoint LDS regions} -> bar -> low B -> bar -> upsample B.
//    B's HBM latency hides under A's tap loop; 4 barriers per 2 tiles,
//    one preamble instead of two.
//  - fill loads dwordx2 (thread owns cols 2t,2t+1): 8 VMEM instr,
//    512B/wave-instr coalesced; 4 swizzled ds_write_b128 per tile.
//  - ax0: two sequential r12 segments per block (barrier between).
//  - numerics identical (same FMA chains, exact IEEE divides).

#define RR 15
#define TAPS 31
#define SIG_PER_FWHM 0.42466090014400953f  // 1/sqrt(8 ln 2)
#define SWB(b) ((b) ^ (((b) >> 3) & 7))

typedef float f4v __attribute__((ext_vector_type(4)));
typedef float f2v __attribute__((ext_vector_type(2)));

__global__ __launch_bounds__(256) void lowres2d_kernel(
    const float* __restrict__ x,
    const float* __restrict__ resolution,
    const int*   __restrict__ axis,
    const float* __restrict__ gap,
    float* __restrict__ out)
{
    const int tid = threadIdx.x;
    const int n   = blockIdx.y;          // image index
    const int bx  = blockIdx.x;          // 0..31 (image-contiguous dispatch)

    const float res = resolution[n];
    const int   ax  = axis[n];
    const float gp  = gap[n];

    const float sig = fmaxf(res * gp * SIG_PER_FWHM, 1e-6f);
    int n_low = (int)floorf(512.0f / res);
    if (n_low < 1) n_low = 1;
    if (n_low > 512) n_low = 512;
    const float nlm1f = (float)(n_low - 1);

    // adaptive radius: normalized weights < 1e-6 outside +-kr (sum >= 1)
    int kr = (int)(sig * 5.2565f) + 1;
    if (kr > RR) kr = RR;
    const int k0 = RR - kr, k1 = RR + 1 + kr;   // fused window k in [k0, k1]
    const int la_lo = kr, la_hi = 510 - kr;     // interior: no reflect needed

    // wd[k] = { we[k+1], dwe[k] }, k = 0..31; we[0]=we[32]=0 implicit
    __shared__ float2 wd[32];
    // overlaid scratch (8192 floats = 32 KB):
    //   ax1: s_imgT = 16B blocks [0,1024), s_lowT = blocks [1024,2048)
    //        (column c half h -> block SWB(2c+h))
    //   ax0: s_lowB[9][512] = 4608 floats at smem base
    __shared__ __align__(16) float smem[8192];
    float (*s_imgT)[4]   = (float (*)[4])smem;
    float (*s_lowT)[4]   = (float (*)[4])(smem + 4096);
    float (*s_lowB)[512] = (float (*)[512])smem;

    if (tid < 32) {
        const int k = tid;
        float r = 0.0f;
        if (k < TAPS) {
            float d = (float)(k - RR) / sig;
            r = expf(-0.5f * d * d);
        }
        float tot = r;
        tot += __shfl_xor(tot, 1, 32);
        tot += __shfl_xor(tot, 2, 32);
        tot += __shfl_xor(tot, 4, 32);
        tot += __shfl_xor(tot, 8, 32);
        tot += __shfl_xor(tot, 16, 32);
        float rm1 = __shfl_up(r, 1, 32);
        if (k == 0) rm1 = 0.0f;
        const float inv = 1.0f / tot;            // tot >= 1 (center tap)
        wd[k] = make_float2(r * inv, (rm1 - r) * inv);
    }
    __syncthreads();

    const size_t base = (size_t)n * (512 * 512);
    const float* img = x + base;
    float* o = out + base;

    if (ax == 0) {
        // ---- ax0: two sequential 8-row segments (r12 body per segment) ---
        const float4* img4 = (const float4*)img;
        const int g  = tid >> 7;                 // group 0/1 (2 waves each)
        const int lt = tid & 127;                // float4 column

        for (int seg = 0; seg < 2; ++seg) {
            const int i0 = bx * 16 + seg * 8;

            // needed low rows for output rows [i0, i0+8)
            float pA = fminf((float)i0 / res, nlm1f);
            int jlo = (int)floorf(pA);
            float pB = fminf((float)(i0 + 7) / res, nlm1f);
            int jhi = (int)floorf(pB) + 1;
            if (jhi > n_low - 1) jhi = n_low - 1;
            if (jhi < jlo) jhi = jlo;
            const int nrows = jhi - jlo + 1;     // <= 9 (res >= 1)

            for (int p = 0; p < nrows; p += 2) { // block-uniform loop
                int rowoff = p + g;              // group-uniform
                int j = jlo + ((rowoff < nrows) ? rowoff : (nrows - 1));
                float pos = fminf((float)j * res, 511.0f);
                float lof = floorf(pos);
                float fr  = pos - lof;
                int   la  = __builtin_amdgcn_readfirstlane((int)lof);
                float4 acc = make_float4(0.0f, 0.0f, 0.0f, 0.0f);
                if (la >= la_lo && la <= la_hi) {    // wave-uniform branch
                    #pragma unroll 4
                    for (int k = k0; k <= k1; ++k) {
                        int t = la - RR + k;         // scalar
                        float2 w = wd[k];
                        float cw = fmaf(fr, w.y, w.x);
                        float4 v = img4[(size_t)(t * 128 + lt)];
                        acc.x = fmaf(cw, v.x, acc.x);
                        acc.y = fmaf(cw, v.y, acc.y);
                        acc.z = fmaf(cw, v.z, acc.z);
                        acc.w = fmaf(cw, v.w, acc.w);
                    }
                } else {
                    for (int k = k0; k <= k1; ++k) {
                        int t = la - RR + k;
                        t = (t < 0)   ? (-1 - t)   : t;  // symmetric reflect
                        t = (t > 511) ? (1023 - t) : t;
                        float2 w = wd[k];
                        float cw = fmaf(fr, w.y, w.x);
                        float4 v = img4[(size_t)(t * 128 + lt)];
                        acc.x = fmaf(cw, v.x, acc.x);
                        acc.y = fmaf(cw, v.y, acc.y);
                        acc.z = fmaf(cw, v.z, acc.z);
                        acc.w = fmaf(cw, v.w, acc.w);
                    }
                }
                if (rowoff < nrows) {            // group-uniform guard
                    ((float4*)&s_lowB[rowoff][0])[lt] = acc;
                }
            }
            __syncthreads();

            // upsample: 2 output rows per pass, group-uniform position math
            #pragma unroll
            for (int p = 0; p < 4; ++p) {
                int i = i0 + p * 2 + g;          // group-uniform
                float pos2 = fminf((float)i / res, nlm1f);  // exact IEEE div
                float l2f  = floorf(pos2);
                float fr2  = pos2 - l2f;
                int lo2 = (int)l2f;              // in [jlo, jhi]
                int hi2 = (lo2 + 1 <= jhi) ? (lo2 + 1) : jhi;
                float4 A = ((float4*)&s_lowB[lo2 - jlo][0])[lt];
                float4 B = ((float4*)&s_lowB[hi2 - jlo][0])[lt];
                float omf2 = 1.0f - fr2;
                f4v ov = { A.x * omf2 + B.x * fr2,
                           A.y * omf2 + B.y * fr2,
                           A.z * omf2 + B.z * fr2,
                           A.w * omf2 + B.w * fr2 };
                __builtin_nontemporal_store(ov, (f4v*)o + (size_t)(i * 128 + lt));
            }
            if (seg == 0) __syncthreads();       // s_lowB reuse protection
        }
    } else {
        // -------- ax1: two 8-row tiles, register-prefetch pipeline --------
        const int h0 = bx * 16;
        const float* imgr = img + (size_t)h0 * 512;

        // low phase: one thread per low column j; per tap 2 ds_read_b128
        // serve all 8 rows; weight+address math amortized 8x.
        auto low_phase = [&]() {
            for (int j = tid; j < n_low; j += 256) {
                float pos = fminf((float)j * res, 511.0f);
                float lof = floorf(pos);
                float fr  = pos - lof;
                int   la  = (int)lof;
                float a0 = 0.f, a1 = 0.f, a2 = 0.f, a3 = 0.f;
                float a4 = 0.f, a5 = 0.f, a6 = 0.f, a7 = 0.f;
                if (la >= la_lo && la <= la_hi) {
                    #pragma unroll 4
                    for (int k = k0; k <= k1; ++k) {
                        int t = la - RR + k;
                        float2 w = wd[k];
                        float cw = fmaf(fr, w.y, w.x);
                        float4 u = *(const float4*)&s_imgT[SWB(2 * t + 0)][0];
                        float4 v = *(const float4*)&s_imgT[SWB(2 * t + 1)][0];
                        a0 = fmaf(cw, u.x, a0);
                        a1 = fmaf(cw, u.y, a1);
                        a2 = fmaf(cw, u.z, a2);
                        a3 = fmaf(cw, u.w, a3);
                        a4 = fmaf(cw, v.x, a4);
                        a5 = fmaf(cw, v.y, a5);
                        a6 = fmaf(cw, v.z, a6);
                        a7 = fmaf(cw, v.w, a7);
                    }
                } else {
                    for (int k = k0; k <= k1; ++k) {
                        int t = la - RR + k;
                        t = (t < 0)   ? (-1 - t)   : t;  // symmetric reflect
                        t = (t > 511) ? (1023 - t) : t;
                        float2 w = wd[k];
                        float cw = fmaf(fr, w.y, w.x);
                        float4 u = *(const float4*)&s_imgT[SWB(2 * t + 0)][0];
                        float4 v = *(const float4*)&s_imgT[SWB(2 * t + 1)][0];
                        a0 = fmaf(cw, u.x, a0);
                        a1 = fmaf(cw, u.y, a1);
                        a2 = fmaf(cw, u.z, a2);
                        a3 = fmaf(cw, u.w, a3);
                        a4 = fmaf(cw, v.x, a4);
                        a5 = fmaf(cw, v.y, a5);
                        a6 = fmaf(cw, v.z, a6);
                        a7 = fmaf(cw, v.w, a7);
                    }
                }
                *(float4*)&s_lowT[SWB(2 * j + 0)][0] = make_float4(a0, a1, a2, a3);
                *(float4*)&s_lowT[SWB(2 * j + 1)][0] = make_float4(a4, a5, a6, a7);
            }
        };

        // upsample: thread owns cols (2t, 2t+1); 8 swizzled b128 reads;
        // 8 coalesced float2 nt stores for rows [hrow, hrow+8)
        auto upsample = [&](int hrow) {
            int ia = 2 * tid, ib = 2 * tid + 1;
            float posa = fminf((float)ia / res, nlm1f);  // exact IEEE div
            float posb = fminf((float)ib / res, nlm1f);
            float lfa = floorf(posa), lfb = floorf(posb);
            float fra = posa - lfa,   frb = posb - lfb;
            int loa = (int)lfa, lob = (int)lfb;
            int hia = (loa + 1 < n_low) ? (loa + 1) : (n_low - 1);
            int hib = (lob + 1 < n_low) ? (lob + 1) : (n_low - 1);
            float oma = 1.0f - fra, omb = 1.0f - frb;
            float4 Aa0 = *(const float4*)&s_lowT[SWB(2 * loa + 0)][0];
            float4 Aa1 = *(const float4*)&s_lowT[SWB(2 * loa + 1)][0];
            float4 Ba0 = *(const float4*)&s_lowT[SWB(2 * hia + 0)][0];
            float4 Ba1 = *(const float4*)&s_lowT[SWB(2 * hia + 1)][0];
            float4 Ab0 = *(const float4*)&s_lowT[SWB(2 * lob + 0)][0];
            float4 Ab1 = *(const float4*)&s_lowT[SWB(2 * lob + 1)][0];
            float4 Bb0 = *(const float4*)&s_lowT[SWB(2 * hib + 0)][0];
            float4 Bb1 = *(const float4*)&s_lowT[SWB(2 * hib + 1)][0];
            float Aar[8] = {Aa0.x, Aa0.y, Aa0.z, Aa0.w, Aa1.x, Aa1.y, Aa1.z, Aa1.w};
            float Bar[8] = {Ba0.x, Ba0.y, Ba0.z, Ba0.w, Ba1.x, Ba1.y, Ba1.z, Ba1.w};
            float Abr[8] = {Ab0.x, Ab0.y, Ab0.z, Ab0.w, Ab1.x, Ab1.y, Ab1.z, Ab1.w};
            float Bbr[8] = {Bb0.x, Bb0.y, Bb0.z, Bb0.w, Bb1.x, Bb1.y, Bb1.z, Bb1.w};
            #pragma unroll
            for (int r = 0; r < 8; ++r) {
                float va = Aar[r] * oma + Bar[r] * fra;
                float vb = Abr[r] * omb + Bbr[r] * frb;
                f2v ov = { va, vb };
                __builtin_nontemporal_store(
                    ov, (f2v*)(o + (size_t)(hrow + r) * 512) + tid);
            }
        };

        // --- tile A fill: 8 dwordx2 loads (cols 2t,2t+1), 4 swizzled
        //     ds_write_b128 (col c rows0-3 -> block SWB(2c), rows4-7 -> +1)
        {
            f2v va[8];
            #pragma unroll
            for (int r = 0; r < 8; ++r)
                va[r] = *(const f2v*)(imgr + (size_t)r * 512 + 2 * tid);
            *(float4*)&s_imgT[SWB(4 * tid + 0)][0] =
                make_float4(va[0].x, va[1].x, va[2].x, va[3].x);
            *(float4*)&s_imgT[SWB(4 * tid + 1)][0] =
                make_float4(va[4].x, va[5].x, va[6].x, va[7].x);
            *(float4*)&s_imgT[SWB(4 * tid + 2)][0] =
                make_float4(va[0].y, va[1].y, va[2].y, va[3].y);
            *(float4*)&s_imgT[SWB(4 * tid + 3)][0] =
                make_float4(va[4].y, va[5].y, va[6].y, va[7].y);
        }
        __syncthreads();                         // bar1: tile A visible

        // --- issue tile B loads early (latency hides under A's low phase)
        f2v vb[8];
        #pragma unroll
        for (int r = 0; r < 8; ++r)
            vb[r] = *(const f2v*)(imgr + (size_t)(8 + r) * 512 + 2 * tid);

        low_phase();                             // tile A lows
        __syncthreads();                         // bar2: s_lowT A ready

        upsample(h0);                            // tile A output
        // write tile B into s_imgT (disjoint from s_lowT; A's imgT reads
        // finished before bar2)
        *(float4*)&s_imgT[SWB(4 * tid + 0)][0] =
            make_float4(vb[0].x, vb[1].x, vb[2].x, vb[3].x);
        *(float4*)&s_imgT[SWB(4 * tid + 1)][0] =
            make_float4(vb[4].x, vb[5].x, vb[6].x, vb[7].x);
        *(float4*)&s_imgT[SWB(4 * tid + 2)][0] =
            make_float4(vb[0].y, vb[1].y, vb[2].y, vb[3].y);
        *(float4*)&s_imgT[SWB(4 * tid + 3)][0] =
            make_float4(vb[4].y, vb[5].y, vb[6].y, vb[7].y);
        __syncthreads();                         // bar3: tile B visible

        low_phase();                             // tile B lows (overwrite
        __syncthreads();                         // s_lowT after bar3; A's
                                                 // upsample reads done)
        upsample(h0 + 8);                        // tile B output
    }
}

extern "C" void kernel_launch(void* const* d_in, const int* in_sizes, int n_in,
                              void* d_out, int out_size, void* d_ws, size_t ws_size,
                              hipStream_t stream) {
    const float* x          = (const float*)d_in[0];
    const float* resolution = (const float*)d_in[1];
    const int*   axis       = (const int*)d_in[2];
    const float* gap        = (const float*)d_in[3];
    float* out = (float*)d_out;

    const int n_img = in_sizes[1];   // B*C = 64

    dim3 grid(32, n_img);            // bx fastest: per-image sequential streaming
    lowres2d_kernel<<<grid, 256, 0, stream>>>(x, resolution, axis, gap, out);
}

// Round 12
// 118.834 us; speedup vs baseline: 1.0529x; 1.0529x over previous
//
#include <hip/hip_runtime.h>
#include <math.h>

// RandomLowRes2D: per-image Gaussian blur (R=15, symmetric pad) + linear
// down/up resample along a per-image runtime axis.
//
// Fusion: low[j] = (1-fr)*s[la] + fr*s[la+1] collapses blur+downsample into a
// single fused filter on img: cw[k] = fmaf(fr, dwe[k], we[k+1]),
// with dwe[k] = we[k] - we[k+1] precomputed.
//
// Round 16 == Round 12 restored verbatim (best measured: bench 120.0us).
// The bracket is complete: 128 blk/img (~38us) > 64 blk/img (r12, best)
// < 32 blk/img 2-tile pipeline (r15, 46-48us cold, bench 125.1). r12 is
// the consolidation optimum; 6 structural theories since were flat/negative.
//
// Round 12 (structural consolidation):
//  - ax1 tile = 8 rows: per-tap weight/address math serves 8 elements;
//    fills, barriers, preambles halve (64 blocks/image).
//  - grid (64, n_img): no early-exit no-op blocks.
//  - LDS layout: 1024 16B blocks per tile, swizzled SWB(b)=b^((b>>3)&7).
//    Column c half h -> block SWB(2c+h). Lane-stride 1/2/4 cols spread
//    perfectly over the 8 bank groups; stride 8 -> 2-way (free, m136).
//  - non-temporal stores for all output (never re-read in-kernel).
//  - numerics identical (same FMA chains, exact IEEE divides).

#define RR 15
#define TAPS 31
#define SIG_PER_FWHM 0.42466090014400953f  // 1/sqrt(8 ln 2)
#define SWB(b) ((b) ^ (((b) >> 3) & 7))

typedef float f4v __attribute__((ext_vector_type(4)));
typedef float f2v __attribute__((ext_vector_type(2)));

__global__ __launch_bounds__(256) void lowres2d_kernel(
    const float* __restrict__ x,
    const float* __restrict__ resolution,
    const int*   __restrict__ axis,
    const float* __restrict__ gap,
    float* __restrict__ out)
{
    const int tid = threadIdx.x;
    const int n   = blockIdx.y;          // image index
    const int bx  = blockIdx.x;          // 0..63 (image-contiguous dispatch)

    const float res = resolution[n];
    const int   ax  = axis[n];
    const float gp  = gap[n];

    const float sig = fmaxf(res * gp * SIG_PER_FWHM, 1e-6f);
    int n_low = (int)floorf(512.0f / res);
    if (n_low < 1) n_low = 1;
    if (n_low > 512) n_low = 512;
    const float nlm1f = (float)(n_low - 1);

    // adaptive radius: normalized weights < 1e-6 outside +-kr (sum >= 1)
    int kr = (int)(sig * 5.2565f) + 1;
    if (kr > RR) kr = RR;
    const int k0 = RR - kr, k1 = RR + 1 + kr;   // fused window k in [k0, k1]
    const int la_lo = kr, la_hi = 510 - kr;     // interior: no reflect needed

    // wd[k] = { we[k+1], dwe[k] }, k = 0..31; we[0]=we[32]=0 implicit
    __shared__ float2 wd[32];
    // overlaid scratch (8192 floats = 32 KB):
    //   ax1: s_imgT = blocks [0,1024), s_lowT = blocks [1024,2048)
    //        (16B blocks; column c half h -> block SWB(2c+h))
    //   ax0: s_lowB[9][512] = 4608 floats at smem base
    __shared__ __align__(16) float smem[8192];
    float (*s_imgT)[4]   = (float (*)[4])smem;
    float (*s_lowT)[4]   = (float (*)[4])(smem + 4096);
    float (*s_lowB)[512] = (float (*)[512])smem;

    if (tid < 32) {
        const int k = tid;
        float r = 0.0f;
        if (k < TAPS) {
            float d = (float)(k - RR) / sig;
            r = expf(-0.5f * d * d);
        }
        float tot = r;
        tot += __shfl_xor(tot, 1, 32);
        tot += __shfl_xor(tot, 2, 32);
        tot += __shfl_xor(tot, 4, 32);
        tot += __shfl_xor(tot, 8, 32);
        tot += __shfl_xor(tot, 16, 32);
        float rm1 = __shfl_up(r, 1, 32);
        if (k == 0) rm1 = 0.0f;
        const float inv = 1.0f / tot;            // tot >= 1 (center tap)
        wd[k] = make_float2(r * inv, (rm1 - r) * inv);
    }
    __syncthreads();

    const size_t base = (size_t)n * (512 * 512);
    const float* img = x + base;
    float* o = out + base;

    if (ax == 0) {
        // ---- ax0: cooperative low rows, float4/lane, 2 rows per pass ----
        const int i0 = bx * 8;
        const int g  = tid >> 7;                 // group 0/1 (2 waves each)
        const int lt = tid & 127;                // float4 column
        const float4* img4 = (const float4*)img;

        // needed low rows for output rows [i0, i0+8)
        float pA = fminf((float)i0 / res, nlm1f);
        int jlo = (int)floorf(pA);
        float pB = fminf((float)(i0 + 7) / res, nlm1f);
        int jhi = (int)floorf(pB) + 1;
        if (jhi > n_low - 1) jhi = n_low - 1;
        if (jhi < jlo) jhi = jlo;
        const int nrows = jhi - jlo + 1;         // <= 9 (res >= 1)

        for (int p = 0; p < nrows; p += 2) {     // block-uniform loop
            int rowoff = p + g;                  // group-uniform
            int j = jlo + ((rowoff < nrows) ? rowoff : (nrows - 1));
            float pos = fminf((float)j * res, 511.0f);
            float lof = floorf(pos);
            float fr  = pos - lof;
            int   la  = __builtin_amdgcn_readfirstlane((int)lof);
            float4 acc = make_float4(0.0f, 0.0f, 0.0f, 0.0f);
            if (la >= la_lo && la <= la_hi) {    // wave-uniform branch
                #pragma unroll 4
                for (int k = k0; k <= k1; ++k) {
                    int t = la - RR + k;         // scalar
                    float2 w = wd[k];
                    float cw = fmaf(fr, w.y, w.x);
                    float4 v = img4[(size_t)(t * 128 + lt)];
                    acc.x = fmaf(cw, v.x, acc.x);
                    acc.y = fmaf(cw, v.y, acc.y);
                    acc.z = fmaf(cw, v.z, acc.z);
                    acc.w = fmaf(cw, v.w, acc.w);
                }
            } else {
                for (int k = k0; k <= k1; ++k) {
                    int t = la - RR + k;
                    t = (t < 0)   ? (-1 - t)   : t;  // symmetric reflect
                    t = (t > 511) ? (1023 - t) : t;
                    float2 w = wd[k];
                    float cw = fmaf(fr, w.y, w.x);
                    float4 v = img4[(size_t)(t * 128 + lt)];
                    acc.x = fmaf(cw, v.x, acc.x);
                    acc.y = fmaf(cw, v.y, acc.y);
                    acc.z = fmaf(cw, v.z, acc.z);
                    acc.w = fmaf(cw, v.w, acc.w);
                }
            }
            if (rowoff < nrows) {                // group-uniform guard
                ((float4*)&s_lowB[rowoff][0])[lt] = acc;
            }
        }
        __syncthreads();

        // upsample: 2 output rows per pass, group-uniform position math
        #pragma unroll
        for (int p = 0; p < 4; ++p) {
            int i = i0 + p * 2 + g;              // group-uniform
            float pos2 = fminf((float)i / res, nlm1f);  // exact IEEE div
            float l2f  = floorf(pos2);
            float fr2  = pos2 - l2f;
            int lo2 = (int)l2f;                  // in [jlo, jhi]
            int hi2 = (lo2 + 1 <= jhi) ? (lo2 + 1) : jhi;  // == min(lo2+1, n_low-1)
            float4 A = ((float4*)&s_lowB[lo2 - jlo][0])[lt];
            float4 B = ((float4*)&s_lowB[hi2 - jlo][0])[lt];
            float omf2 = 1.0f - fr2;
            f4v ov = { A.x * omf2 + B.x * fr2,
                       A.y * omf2 + B.y * fr2,
                       A.z * omf2 + B.z * fr2,
                       A.w * omf2 + B.w * fr2 };
            __builtin_nontemporal_store(ov, (f4v*)o + (size_t)(i * 128 + lt));
        }
    } else {
        // -------- ax1: 8-row transposed+swizzled LDS tile ----------------
        const int h0 = bx * 8;
        const float* imgr = img + (size_t)h0 * 512;

        // fill: 2 columns per thread, 8 coalesced scalar loads per column
        // (each wave-instr = 256 contiguous bytes of one row), 2 swizzled
        // ds_write_b128 per column.
        #pragma unroll
        for (int p = 0; p < 2; ++p) {
            int c = p * 256 + tid;
            float v0 = imgr[0 * 512 + c];
            float v1 = imgr[1 * 512 + c];
            float v2 = imgr[2 * 512 + c];
            float v3 = imgr[3 * 512 + c];
            float v4 = imgr[4 * 512 + c];
            float v5 = imgr[5 * 512 + c];
            float v6 = imgr[6 * 512 + c];
            float v7 = imgr[7 * 512 + c];
            *(float4*)&s_imgT[SWB(2 * c + 0)][0] = make_float4(v0, v1, v2, v3);
            *(float4*)&s_imgT[SWB(2 * c + 1)][0] = make_float4(v4, v5, v6, v7);
        }
        __syncthreads();

        // low phase: one thread per low column j; per tap 2 ds_read_b128
        // serve ALL 8 rows; weight+address math amortized 8x.
        for (int j = tid; j < n_low; j += 256) {
            float pos = fminf((float)j * res, 511.0f);
            float lof = floorf(pos);
            float fr  = pos - lof;
            int   la  = (int)lof;
            float a0 = 0.f, a1 = 0.f, a2 = 0.f, a3 = 0.f;
            float a4 = 0.f, a5 = 0.f, a6 = 0.f, a7 = 0.f;
            if (la >= la_lo && la <= la_hi) {
                #pragma unroll 4
                for (int k = k0; k <= k1; ++k) {
                    int t = la - RR + k;
                    float2 w = wd[k];
                    float cw = fmaf(fr, w.y, w.x);
                    float4 u = *(const float4*)&s_imgT[SWB(2 * t + 0)][0];
                    float4 v = *(const float4*)&s_imgT[SWB(2 * t + 1)][0];
                    a0 = fmaf(cw, u.x, a0);
                    a1 = fmaf(cw, u.y, a1);
                    a2 = fmaf(cw, u.z, a2);
                    a3 = fmaf(cw, u.w, a3);
                    a4 = fmaf(cw, v.x, a4);
                    a5 = fmaf(cw, v.y, a5);
                    a6 = fmaf(cw, v.z, a6);
                    a7 = fmaf(cw, v.w, a7);
                }
            } else {
                for (int k = k0; k <= k1; ++k) {
                    int t = la - RR + k;
                    t = (t < 0)   ? (-1 - t)   : t;  // symmetric reflect
                    t = (t > 511) ? (1023 - t) : t;
                    float2 w = wd[k];
                    float cw = fmaf(fr, w.y, w.x);
                    float4 u = *(const float4*)&s_imgT[SWB(2 * t + 0)][0];
                    float4 v = *(const float4*)&s_imgT[SWB(2 * t + 1)][0];
                    a0 = fmaf(cw, u.x, a0);
                    a1 = fmaf(cw, u.y, a1);
                    a2 = fmaf(cw, u.z, a2);
                    a3 = fmaf(cw, u.w, a3);
                    a4 = fmaf(cw, v.x, a4);
                    a5 = fmaf(cw, v.y, a5);
                    a6 = fmaf(cw, v.z, a6);
                    a7 = fmaf(cw, v.w, a7);
                }
            }
            *(float4*)&s_lowT[SWB(2 * j + 0)][0] = make_float4(a0, a1, a2, a3);
            *(float4*)&s_lowT[SWB(2 * j + 1)][0] = make_float4(a4, a5, a6, a7);
        }
        __syncthreads();

        // upsample: thread owns adjacent cols (2t, 2t+1); position math per
        // column serves 8 rows; 8 swizzled b128 reads; 8 coalesced float2
        // non-temporal stores.
        {
            int ia = 2 * tid, ib = 2 * tid + 1;
            float posa = fminf((float)ia / res, nlm1f);  // exact IEEE div
            float posb = fminf((float)ib / res, nlm1f);
            float lfa = floorf(posa), lfb = floorf(posb);
            float fra = posa - lfa,   frb = posb - lfb;
            int loa = (int)lfa, lob = (int)lfb;
            int hia = (loa + 1 < n_low) ? (loa + 1) : (n_low - 1);
            int hib = (lob + 1 < n_low) ? (lob + 1) : (n_low - 1);
            float oma = 1.0f - fra, omb = 1.0f - frb;
            float4 Aa0 = *(const float4*)&s_lowT[SWB(2 * loa + 0)][0];
            float4 Aa1 = *(const float4*)&s_lowT[SWB(2 * loa + 1)][0];
            float4 Ba0 = *(const float4*)&s_lowT[SWB(2 * hia + 0)][0];
            float4 Ba1 = *(const float4*)&s_lowT[SWB(2 * hia + 1)][0];
            float4 Ab0 = *(const float4*)&s_lowT[SWB(2 * lob + 0)][0];
            float4 Ab1 = *(const float4*)&s_lowT[SWB(2 * lob + 1)][0];
            float4 Bb0 = *(const float4*)&s_lowT[SWB(2 * hib + 0)][0];
            float4 Bb1 = *(const float4*)&s_lowT[SWB(2 * hib + 1)][0];
            float Aar[8] = {Aa0.x, Aa0.y, Aa0.z, Aa0.w, Aa1.x, Aa1.y, Aa1.z, Aa1.w};
            float Bar[8] = {Ba0.x, Ba0.y, Ba0.z, Ba0.w, Ba1.x, Ba1.y, Ba1.z, Ba1.w};
            float Abr[8] = {Ab0.x, Ab0.y, Ab0.z, Ab0.w, Ab1.x, Ab1.y, Ab1.z, Ab1.w};
            float Bbr[8] = {Bb0.x, Bb0.y, Bb0.z, Bb0.w, Bb1.x, Bb1.y, Bb1.z, Bb1.w};
            #pragma unroll
            for (int r = 0; r < 8; ++r) {
                float va = Aar[r] * oma + Bar[r] * fra;
                float vb = Abr[r] * omb + Bbr[r] * frb;
                f2v ov = { va, vb };
                __builtin_nontemporal_store(
                    ov, (f2v*)(o + (size_t)(h0 + r) * 512) + tid);
            }
        }
    }
}

extern "C" void kernel_launch(void* const* d_in, const int* in_sizes, int n_in,
                              void* d_out, int out_size, void* d_ws, size_t ws_size,
                              hipStream_t stream) {
    const float* x          = (const float*)d_in[0];
    const float* resolution = (const float*)d_in[1];
    const int*   axis       = (const int*)d_in[2];
    const float* gap        = (const float*)d_in[3];
    float* out = (float*)d_out;

    const int n_img = in_sizes[1];   // B*C = 64

    dim3 grid(64, n_img);            // bx fastest: per-image sequential streaming
    lowres2d_kernel<<<grid, 256, 0, stream>>>(x, resolution, axis, gap, out);
}